// Round 7
// baseline (797.554 us; speedup 1.0000x reference)
//
#include <hip/hip_runtime.h>
#include <hip/hip_bf16.h>
#include <math.h>

// Problem constants
#define B_ 8
#define Q_ 64
#define S_ 48
#define T_ 128
#define H_ 768
#define NH_ 12
#define HD_ 64
#define FF_ 3072

typedef float f32x4 __attribute__((ext_vector_type(4)));
typedef short s16x8 __attribute__((ext_vector_type(8)));
typedef short s16x4 __attribute__((ext_vector_type(4)));

__device__ __forceinline__ float ldT(const float* p, size_t i) { return p[i]; }
__device__ __forceinline__ float ldT(const __hip_bfloat16* p, size_t i) { return __bfloat162float(p[i]); }
__device__ __forceinline__ void stT(float* p, size_t i, float v) { p[i] = v; }
__device__ __forceinline__ void stT(__hip_bfloat16* p, size_t i, float v) { p[i] = __float2bfloat16(v); }

__device__ __forceinline__ short f2bf(float f) {
  __hip_bfloat16 h = __float2bfloat16(f);
  return *reinterpret_cast<short*>(&h);
}

__device__ __forceinline__ float gelu_f(float x) {
  return 0.5f * x * (1.0f + erff(x * 0.70710678118654752f));
}

// async global->LDS, 16B per lane
__device__ __forceinline__ void gld_lds16(const void* g, void* l) {
  __builtin_amdgcn_global_load_lds(
      (const __attribute__((address_space(1))) void*)g,
      (__attribute__((address_space(3))) void*)l, 16, 0, 0);
}

#define FENCE() asm volatile("" ::: "memory")
#define BARRIER() do { FENCE(); __builtin_amdgcn_s_barrier(); FENCE(); } while (0)
#define WAITV(n) asm volatile("s_waitcnt vmcnt(" #n ")" ::: "memory")

// ---------------------------------------------------------------------------
// Ring-pipelined MFMA bf16 GEMM: C[M,N] = act(A[M,K] @ BT[N,K]^T + bias)
// BM=BN=256, BK=64. 512 threads = 8 waves (2M x 4N), per-wave 128x64
// (A-frag reuse 4x, B-frag reuse 8x -> LDS-read ~ MFMA balanced).
// LDS = ring of 9 x 16KB half-tiles (144KB). K-tile t occupies slots
// 4t..4t+3 = {A-rows0-127, A-rows128-255, B0-127, B128-255} (ring = slot%9).
// During tile t's 4 phases we stage slots 4t+5..4t+8 (overwriting tile
// t-1's slots, whose reads finished at the last boundary barrier).
// Boundary gate: vmcnt(2) = all halves of tile t+1 landed (vmcnt is
// in-order), only the newest half (slot 4t+8) may remain in flight.
// Phase = {ds_read frag subtile; stage 1 half; barrier; setprio(1);
// 16 MFMA; setprio(0); barrier}. Reads/phase: 12/8/4/0.
// Chunk swizzle: 16B chunk kc of row at slot kc^(row&7) (involution),
// pre-swizzled global source + linear gld_lds dest (rule #21).
// Requires M%256==0, N%256==0, K%64==0, NT>=3, grid %8==0.
// ---------------------------------------------------------------------------
template<int K, typename OT, bool BIAS, bool GELU>
__global__ __launch_bounds__(512, 2) void gemm9r(
    const __hip_bfloat16* __restrict__ A,   // [M,K]
    const __hip_bfloat16* __restrict__ BT,  // [N,K]
    const float* __restrict__ bias, OT* __restrict__ C,
    int N, int nbx)
{
  constexpr int NT = K / 64;
  static_assert(NT >= 3, "need at least 3 K-tiles");
  __shared__ __align__(16) char sm[9 * 16384];

  // XCD-aware chunked swizzle (grid %8 == 0 for all launches)
  int wg = blockIdx.x;
  const int q8 = gridDim.x >> 3;
  wg = (wg & 7) * q8 + (wg >> 3);
  const int bm = wg / nbx;
  const int bn = wg % nbx;
  const int m0 = bm * 256, n0 = bn * 256;

  const int tid = threadIdx.x;
  const int lane = tid & 63;
  const int wid = tid >> 6;        // 0..7
  const int wm = wid >> 2;         // 0..1 : which 128-row half of the tile
  const int wc = wid & 3;          // 0..3 : which 64-col block
  const int bh = wc >> 1;          // which B-half this wave reads
  const int kcg = lane >> 4;       // 0..3
  const int rl = lane & 15;

  // staging: each half-tile = [128 rows][8 slots] of 16B chunks (1024);
  // thread owns chunks tid (row r, slot s) and tid+512 (row r+64, same s).
  const int c1r = tid >> 3;
  const int c1k = (tid & 7) ^ (c1r & 7);   // pre-swizzled k-chunk

  auto stage_slot = [&](int slot) {
    const int tile = slot >> 2, half = slot & 3;
    const __hip_bfloat16* mb =
        (half < 2 ? A + (size_t)m0 * K : BT + (size_t)n0 * K)
        + (size_t)(half & 1) * 128 * K + tile * 64;
    char* lb = sm + (slot % 9) * 16384;
    gld_lds16(mb + (size_t)c1r * K + c1k * 8, lb + tid * 16);
    gld_lds16(mb + (size_t)(c1r + 64) * K + c1k * 8, lb + (tid + 512) * 16);
  };

  // fragment within-half byte offsets (kch=1 adds ^64: chunk+4 == chunk^4)
  int woffA[8], woffB[4];
  #pragma unroll
  for (int mf = 0; mf < 8; ++mf) {
    const int lr = mf * 16 + rl;
    woffA[mf] = lr * 128 + ((kcg ^ (lr & 7)) << 4);
  }
  #pragma unroll
  for (int nf = 0; nf < 4; ++nf) {
    const int lr = (wc & 1) * 64 + nf * 16 + rl;
    woffB[nf] = lr * 128 + ((kcg ^ (lr & 7)) << 4);
  }

  f32x4 acc[8][4] = {};

  // prologue: tile0 (slots 0-3) + tile1's first half (slot 4)
  stage_slot(0); stage_slot(1); stage_slot(2); stage_slot(3); stage_slot(4);
  WAITV(2);                      // tile0's 8 loads landed; slot4 may fly
  BARRIER();

  int ringT = 0;                 // (4*t) % 9
  #pragma unroll 1
  for (int t = 0; t < NT; ++t) {
    int rA = ringT + wm;      if (rA >= 9) rA -= 9;
    int rB = ringT + 2 + bh;  if (rB >= 9) rB -= 9;
    const char* baseA = sm + rA * 16384;
    const char* baseB = sm + rB * 16384;

    s16x8 af0[4][2], af1[4][2], bf[2][2];

    // ---- Phase 1 (m0-3 x n0-1): read A0-3 + B0-1; stage slot 4t+5
    #pragma unroll
    for (int mf = 0; mf < 4; ++mf)
      #pragma unroll
      for (int kch = 0; kch < 2; ++kch)
        af0[mf][kch] = *(const s16x8*)(baseA + (woffA[mf] ^ (kch << 6)));
    #pragma unroll
    for (int nf = 0; nf < 2; ++nf)
      #pragma unroll
      for (int kch = 0; kch < 2; ++kch)
        bf[nf][kch] = *(const s16x8*)(baseB + (woffB[nf] ^ (kch << 6)));
    if (4 * t + 5 < 4 * NT) stage_slot(4 * t + 5);
    BARRIER();
    __builtin_amdgcn_s_setprio(1);
    #pragma unroll
    for (int kch = 0; kch < 2; ++kch)
      #pragma unroll
      for (int mf = 0; mf < 4; ++mf)
        #pragma unroll
        for (int nf = 0; nf < 2; ++nf)
          acc[mf][nf] = __builtin_amdgcn_mfma_f32_16x16x32_bf16(
              af0[mf][kch], bf[nf][kch], acc[mf][nf], 0, 0, 0);
    __builtin_amdgcn_s_setprio(0);
    BARRIER();

    // ---- Phase 2 (m4-7 x n0-1): read A4-7; stage slot 4t+6
    #pragma unroll
    for (int mf = 0; mf < 4; ++mf)
      #pragma unroll
      for (int kch = 0; kch < 2; ++kch)
        af1[mf][kch] = *(const s16x8*)(baseA + (woffA[4 + mf] ^ (kch << 6)));
    if (4 * t + 6 < 4 * NT) stage_slot(4 * t + 6);
    BARRIER();
    __builtin_amdgcn_s_setprio(1);
    #pragma unroll
    for (int kch = 0; kch < 2; ++kch)
      #pragma unroll
      for (int mf = 0; mf < 4; ++mf)
        #pragma unroll
        for (int nf = 0; nf < 2; ++nf)
          acc[4 + mf][nf] = __builtin_amdgcn_mfma_f32_16x16x32_bf16(
              af1[mf][kch], bf[nf][kch], acc[4 + mf][nf], 0, 0, 0);
    __builtin_amdgcn_s_setprio(0);
    BARRIER();

    // ---- Phase 3 (m4-7 x n2-3): read B2-3 (bf dead->reuse); stage 4t+7
    #pragma unroll
    for (int nf = 0; nf < 2; ++nf)
      #pragma unroll
      for (int kch = 0; kch < 2; ++kch)
        bf[nf][kch] = *(const s16x8*)(baseB + (woffB[2 + nf] ^ (kch << 6)));
    if (4 * t + 7 < 4 * NT) stage_slot(4 * t + 7);
    BARRIER();
    __builtin_amdgcn_s_setprio(1);
    #pragma unroll
    for (int kch = 0; kch < 2; ++kch)
      #pragma unroll
      for (int mf = 0; mf < 4; ++mf)
        #pragma unroll
        for (int nf = 0; nf < 2; ++nf)
          acc[4 + mf][2 + nf] = __builtin_amdgcn_mfma_f32_16x16x32_bf16(
              af1[mf][kch], bf[nf][kch], acc[4 + mf][2 + nf], 0, 0, 0);
    __builtin_amdgcn_s_setprio(0);
    BARRIER();

    // ---- Phase 4 (m0-3 x n2-3): no reads; stage slot 4t+8
    if (4 * t + 8 < 4 * NT) stage_slot(4 * t + 8);
    __builtin_amdgcn_s_setprio(1);
    #pragma unroll
    for (int kch = 0; kch < 2; ++kch)
      #pragma unroll
      for (int mf = 0; mf < 4; ++mf)
        #pragma unroll
        for (int nf = 0; nf < 2; ++nf)
          acc[mf][2 + nf] = __builtin_amdgcn_mfma_f32_16x16x32_bf16(
              af0[mf][kch], bf[nf][kch], acc[mf][2 + nf], 0, 0, 0);
    __builtin_amdgcn_s_setprio(0);

    // ---- boundary gate: tile t+1 fully landed (only slot 4t+8 may fly)
    if (t < NT - 1) {
      if (t < NT - 2) WAITV(2);
      else            WAITV(0);
      BARRIER();
    }
    ringT += 4; if (ringT >= 9) ringT -= 9;
  }

  // epilogue: C/D layout col=lane&15, row=(lane>>4)*4+r  [m89-verified]
  const int colb = n0 + wc * 64 + rl;
  const int rowb = m0 + wm * 128 + (lane >> 4) * 4;
  float bv[4];
  #pragma unroll
  for (int nf = 0; nf < 4; ++nf) bv[nf] = BIAS ? bias[colb + nf * 16] : 0.0f;
  #pragma unroll
  for (int mf = 0; mf < 8; ++mf) {
    #pragma unroll
    for (int r = 0; r < 4; ++r) {
      const int row = rowb + mf * 16 + r;
      #pragma unroll
      for (int nf = 0; nf < 4; ++nf) {
        float v = acc[mf][nf][r] + bv[nf];
        if (GELU) v = gelu_f(v);
        stT(C, (size_t)row * N + colb + nf * 16, v);
      }
    }
  }
}

// ---------------------------------------------------------------------------
// fp32 LDS-tiled GEMM (q-projection only), templated output
// ---------------------------------------------------------------------------
template<typename OT>
__global__ __launch_bounds__(256) void gemm64(
    const float* __restrict__ A, const float* __restrict__ W,
    OT* __restrict__ C, int M, int N, int K)
{
  __shared__ float As[16][65];
  __shared__ float Ws[16][65];
  const int tid = threadIdx.x;
  const int m0 = blockIdx.y * 64;
  const int n0 = blockIdx.x * 64;
  const int tx = (tid & 15) * 4;
  const int ty = (tid >> 4) * 4;
  float acc[4][4] = {};

  for (int k0 = 0; k0 < K; k0 += 16) {
    #pragma unroll
    for (int r = 0; r < 4; ++r) {
      int idx = tid + r * 256;
      int mm = idx >> 4, kk = idx & 15;
      As[kk][mm] = A[(size_t)(m0 + mm) * K + (k0 + kk)];
    }
    #pragma unroll
    for (int r = 0; r < 4; ++r) {
      int idx = tid + r * 256;
      int kk = idx >> 6, nn = idx & 63;
      Ws[kk][nn] = W[(size_t)(k0 + kk) * N + (n0 + nn)];
    }
    __syncthreads();
    #pragma unroll
    for (int kk = 0; kk < 16; ++kk) {
      float a[4], b[4];
      #pragma unroll
      for (int i = 0; i < 4; ++i) a[i] = As[kk][ty + i];
      #pragma unroll
      for (int j = 0; j < 4; ++j) b[j] = Ws[kk][tx + j];
      #pragma unroll
      for (int i = 0; i < 4; ++i)
        #pragma unroll
        for (int j = 0; j < 4; ++j) acc[i][j] += a[i] * b[j];
    }
    __syncthreads();
  }
  #pragma unroll
  for (int i = 0; i < 4; ++i)
    #pragma unroll
    for (int j = 0; j < 4; ++j)
      stT(C, (size_t)(m0 + ty + i) * N + (n0 + tx + j), acc[i][j]);
}

// ---------------------------------------------------------------------------
// weight transpose-cast: W[K,N] f32 -> WT[N,K] bf16
// ---------------------------------------------------------------------------
__global__ __launch_bounds__(256) void transpose_cast(
    const float* __restrict__ W, __hip_bfloat16* __restrict__ WT, int K, int N)
{
  __shared__ float t[32][33];
  const int n0 = blockIdx.x * 32, k0 = blockIdx.y * 32;
  const int x = threadIdx.x & 31, y4 = (threadIdx.x >> 5) * 4;
  #pragma unroll
  for (int i = 0; i < 4; ++i)
    t[y4 + i][x] = W[(size_t)(k0 + y4 + i) * N + n0 + x];
  __syncthreads();
  #pragma unroll
  for (int i = 0; i < 4; ++i)
    WT[(size_t)(n0 + y4 + i) * K + k0 + x] = __float2bfloat16(t[x][y4 + i]);
}

// elementwise cast f32 -> bf16, 4 elems/thread
__global__ __launch_bounds__(256) void cast_f32_bf16(
    const float* __restrict__ x, __hip_bfloat16* __restrict__ y, size_t n4)
{
  const size_t i = (size_t)blockIdx.x * 256 + threadIdx.x;
  if (i >= n4) return;
  const float4 v = ((const float4*)x)[i];
  __hip_bfloat16 o[4] = { __float2bfloat16(v.x), __float2bfloat16(v.y),
                          __float2bfloat16(v.z), __float2bfloat16(v.w) };
  *(ushort4*)(y + i * 4) = *(ushort4*)o;
}

// ---------------------------------------------------------------------------
// MFMA attention. Block = (s, h, b). 256 threads = 4 waves (2x2).  (R4, unchanged)
// ---------------------------------------------------------------------------
__global__ __launch_bounds__(256) void attn_mfma(
    const __hip_bfloat16* __restrict__ qp,   // [B*Q][H] bf16
    const __hip_bfloat16* __restrict__ kvp,  // [B*S*T][H] bf16
    const int* __restrict__ mask,
    __hip_bfloat16* __restrict__ res)        // [B,Q,S,H] bf16
{
  const int s = blockIdx.x, h = blockIdx.y, b = blockIdx.z;
  __shared__ __align__(16) char lds[66048];
  char* Ks = lds;
  char* VT = lds + 16384;
  char* SC = lds + 32768;
  float* mv = (float*)(lds + 65536);

  const int tid = threadIdx.x;
  const int lane = tid & 63;
  const int wid = tid >> 6;
  const int wr = wid >> 1, wc = wid & 1;
  const int kcg = lane >> 4, rl = lane & 15;

  if (tid < 128) mv[tid] = (float)mask[((size_t)b * S_ + s) * T_ + tid] * -10000.0f;

  {
    const __hip_bfloat16* qb = qp + ((size_t)b * Q_) * H_ + h * HD_;
    #pragma unroll
    for (int r = 0; r < 2; ++r) {
      const int c = tid + r * 256;
      const int qq = c >> 3, sc = c & 7;
      const int kc8 = sc ^ (qq & 7);
      gld_lds16(qb + (size_t)qq * H_ + kc8 * 8, SC + c * 16);
    }
  }
  {
    const int kc8 = tid & 7, tg = tid >> 3;
    const int t0 = tg * 4;
    const __hip_bfloat16* kb = kvp + (((size_t)b * S_ + s) * T_) * H_ + h * HD_ + kc8 * 8;
    s16x8 r0 = *(const s16x8*)(kb + (size_t)(t0 + 0) * H_);
    s16x8 r1 = *(const s16x8*)(kb + (size_t)(t0 + 1) * H_);
    s16x8 r2 = *(const s16x8*)(kb + (size_t)(t0 + 2) * H_);
    s16x8 r3 = *(const s16x8*)(kb + (size_t)(t0 + 3) * H_);
    *(s16x8*)(Ks + (t0 + 0) * 128 + ((kc8 ^ ((t0 + 0) & 7)) << 4)) = r0;
    *(s16x8*)(Ks + (t0 + 1) * 128 + ((kc8 ^ ((t0 + 1) & 7)) << 4)) = r1;
    *(s16x8*)(Ks + (t0 + 2) * 128 + ((kc8 ^ ((t0 + 2) & 7)) << 4)) = r2;
    *(s16x8*)(Ks + (t0 + 3) * 128 + ((kc8 ^ ((t0 + 3) & 7)) << 4)) = r3;
    const int tc = tg >> 1;
    const int toff = (tg & 1) * 8;
    #pragma unroll
    for (int j = 0; j < 8; ++j) {
      s16x4 v4 = { r0[j], r1[j], r2[j], r3[j] };
      const int d = kc8 * 8 + j;
      *(s16x4*)(VT + d * 256 + ((tc ^ (d & 15)) << 4) + toff) = v4;
    }
  }
  __syncthreads();

  f32x4 acc[2][4] = {};
  {
    s16x8 af[2][2], bf[2][4];
    #pragma unroll
    for (int kk = 0; kk < 2; ++kk) {
      #pragma unroll
      for (int m = 0; m < 2; ++m) {
        const int q = wr * 32 + m * 16 + rl;
        const int kc8 = kk * 4 + kcg;
        af[kk][m] = *(const s16x8*)(SC + q * 128 + ((kc8 ^ (q & 7)) << 4));
      }
      #pragma unroll
      for (int n = 0; n < 4; ++n) {
        const int t = wc * 64 + n * 16 + rl;
        const int kc8 = kk * 4 + kcg;
        bf[kk][n] = *(const s16x8*)(Ks + t * 128 + ((kc8 ^ (t & 7)) << 4));
      }
    }
    #pragma unroll
    for (int kk = 0; kk < 2; ++kk)
      #pragma unroll
      for (int m = 0; m < 2; ++m)
        #pragma unroll
        for (int n = 0; n < 4; ++n)
          acc[m][n] = __builtin_amdgcn_mfma_f32_16x16x32_bf16(af[kk][m], bf[kk][n], acc[m][n], 0, 0, 0);
  }
  __syncthreads();

  #pragma unroll
  for (int m = 0; m < 2; ++m)
    #pragma unroll
    for (int n = 0; n < 4; ++n)
      #pragma unroll
      for (int r = 0; r < 4; ++r) {
        const int q = wr * 32 + m * 16 + (lane >> 4) * 4 + r;
        const int t = wc * 64 + n * 16 + rl;
        const int tc32 = t >> 2;
        *(float*)(SC + q * 512 + ((tc32 ^ (q & 31)) << 4) + (t & 3) * 4) =
            acc[m][n][r] * 0.125f + mv[t];
      }
  __syncthreads();

  {
    const int q = tid >> 2, quarter = tid & 3;
    float vals[32];
    #pragma unroll
    for (int j = 0; j < 8; ++j) {
      const int tc32 = quarter * 8 + j;
      const f32x4 c = *(const f32x4*)(SC + q * 512 + ((tc32 ^ (q & 31)) << 4));
      vals[j * 4 + 0] = c[0]; vals[j * 4 + 1] = c[1];
      vals[j * 4 + 2] = c[2]; vals[j * 4 + 3] = c[3];
    }
    float mx = -1e30f;
    #pragma unroll
    for (int i = 0; i < 32; ++i) mx = fmaxf(mx, vals[i]);
    mx = fmaxf(mx, __shfl_xor(mx, 1, 64));
    mx = fmaxf(mx, __shfl_xor(mx, 2, 64));
    float sum = 0.0f;
    #pragma unroll
    for (int i = 0; i < 32; ++i) { vals[i] = expf(vals[i] - mx); sum += vals[i]; }
    sum += __shfl_xor(sum, 1, 64);
    sum += __shfl_xor(sum, 2, 64);
    const float inv = 1.0f / sum;
    #pragma unroll
    for (int jj = 0; jj < 4; ++jj) {
      const int tcp = quarter * 4 + jj;
      s16x8 pk;
      #pragma unroll
      for (int i = 0; i < 8; ++i) pk[i] = f2bf(vals[jj * 8 + i] * inv);
      *(s16x8*)(SC + q * 512 + ((tcp ^ (q & 15)) << 4)) = pk;
    }
  }
  __syncthreads();

  f32x4 oacc[2][2] = {};
  #pragma unroll
  for (int kt = 0; kt < 4; ++kt) {
    s16x8 pa[2], vb[2];
    #pragma unroll
    for (int m = 0; m < 2; ++m) {
      const int q = wr * 32 + m * 16 + rl;
      const int tcp = kt * 4 + kcg;
      pa[m] = *(const s16x8*)(SC + q * 512 + ((tcp ^ (q & 15)) << 4));
    }
    #pragma unroll
    for (int n = 0; n < 2; ++n) {
      const int d = wc * 32 + n * 16 + rl;
      const int tc = kt * 4 + kcg;
      vb[n] = *(const s16x8*)(VT + d * 256 + ((tc ^ (d & 15)) << 4));
    }
    #pragma unroll
    for (int m = 0; m < 2; ++m)
      #pragma unroll
      for (int n = 0; n < 2; ++n)
        oacc[m][n] = __builtin_amdgcn_mfma_f32_16x16x32_bf16(pa[m], vb[n], oacc[m][n], 0, 0, 0);
  }
  #pragma unroll
  for (int m = 0; m < 2; ++m)
    #pragma unroll
    for (int n = 0; n < 2; ++n)
      #pragma unroll
      for (int r = 0; r < 4; ++r) {
        const int q = wr * 32 + m * 16 + (lane >> 4) * 4 + r;
        const int d = wc * 32 + n * 16 + rl;
        res[(((size_t)b * Q_ + q) * S_ + s) * H_ + h * HD_ + d] =
            __float2bfloat16(oacc[m][n][r]);
      }
}

// ---------------------------------------------------------------------------
// Row LayerNorm over H=768, templated in/out dtypes.
// ---------------------------------------------------------------------------
template<bool ADD, typename IT, typename OT>
__global__ __launch_bounds__(256) void ln_kernel(
    const IT* __restrict__ X, const IT* __restrict__ X2,
    const float* __restrict__ g, const float* __restrict__ bta,
    OT* __restrict__ Y)
{
  const size_t row = blockIdx.x;
  const int tid = threadIdx.x;
  float v[3];
  #pragma unroll
  for (int i = 0; i < 3; ++i) {
    int c = tid + i * 256;
    v[i] = ldT(X, row * H_ + c);
    if (ADD) v[i] += ldT(X2, row * H_ + c);
  }
  float sum = v[0] + v[1] + v[2];
  #pragma unroll
  for (int off = 32; off > 0; off >>= 1) sum += __shfl_down(sum, off, 64);
  __shared__ float red[8];
  const int w = tid >> 6;
  if ((tid & 63) == 0) red[w] = sum;
  __syncthreads();
  const float mean = (red[0] + red[1] + red[2] + red[3]) * (1.0f / 768.0f);
  float vs = 0.0f;
  #pragma unroll
  for (int i = 0; i < 3; ++i) { v[i] -= mean; vs += v[i] * v[i]; }
  #pragma unroll
  for (int off = 32; off > 0; off >>= 1) vs += __shfl_down(vs, off, 64);
  if ((tid & 63) == 0) red[4 + w] = vs;
  __syncthreads();
  const float rstd = rsqrtf((red[4] + red[5] + red[6] + red[7]) * (1.0f / 768.0f) + 1e-12f);
  #pragma unroll
  for (int i = 0; i < 3; ++i) {
    int c = tid + i * 256;
    stT(Y, row * H_ + c, v[i] * rstd * g[c] + bta[c]);
  }
}

// ---------------------------------------------------------------------------
extern "C" void kernel_launch(void* const* d_in, const int* in_sizes, int n_in,
                              void* d_out, int out_size, void* d_ws, size_t ws_size,
                              hipStream_t stream) {
  const float* q    = (const float*)d_in[0];
  const float* k    = (const float*)d_in[1];
  const int*   mask = (const int*)d_in[2];
  const float* Wq   = (const float*)d_in[3];
  const float* Wkv  = (const float*)d_in[4];
  const float* Wo   = (const float*)d_in[5];
  const float* bo   = (const float*)d_in[6];
  const float* ln1g = (const float*)d_in[7];
  const float* ln1b = (const float*)d_in[8];
  const float* W1   = (const float*)d_in[9];
  const float* b1   = (const float*)d_in[10];
  const float* W2   = (const float*)d_in[11];
  const float* b2   = (const float*)d_in[12];
  const float* ln2g = (const float*)d_in[13];
  const float* ln2b = (const float*)d_in[14];
  float* out = (float*)d_out;

  const int MROWS = B_ * Q_ * S_;           // 24576
  const int KVROWS = B_ * S_ * T_;          // 49152

  // workspace layout (bytes), lifetime-based reuse:
  char* ws = (char*)d_ws;
  __hip_bfloat16* kbf  = (__hip_bfloat16*)ws;                        // 75.5MB
  __hip_bfloat16* kvp  = (__hip_bfloat16*)(ws + 75497472);           // 75.5MB
  __hip_bfloat16* ffn1 = (__hip_bfloat16*)ws;                        // 151MB (reuse)
  __hip_bfloat16* ares = (__hip_bfloat16*)(ws + 150994944);          // 37.7MB
  __hip_bfloat16* ffn2 = ares;                                       // reuse
  __hip_bfloat16* aln  = (__hip_bfloat16*)(ws + 188743680);          // 37.7MB
  __hip_bfloat16* qp   = (__hip_bfloat16*)(ws + 226492416);          // 0.8MB (bf16)
  __hip_bfloat16* WkvT = (__hip_bfloat16*)(ws + 228065280);
  __hip_bfloat16* WoT  = (__hip_bfloat16*)(ws + 229244928);
  __hip_bfloat16* W1T  = (__hip_bfloat16*)(ws + 230424576);
  __hip_bfloat16* W2T  = (__hip_bfloat16*)(ws + 235143168);

  dim3 blk(256);
  dim3 blk9(512);

  // weight prep
  transpose_cast<<<dim3(24, 24), blk, 0, stream>>>(Wkv, WkvT, H_, H_);
  transpose_cast<<<dim3(24, 24), blk, 0, stream>>>(Wo, WoT, H_, H_);
  transpose_cast<<<dim3(96, 24), blk, 0, stream>>>(W1, W1T, H_, FF_);
  transpose_cast<<<dim3(24, 96), blk, 0, stream>>>(W2, W2T, FF_, H_);
  cast_f32_bf16<<<dim3((KVROWS * H_ / 4 + 255) / 256), blk, 0, stream>>>(
      k, kbf, (size_t)KVROWS * H_ / 4);

  // 1. q projection (fp32 in, bf16 out)
  gemm64<__hip_bfloat16><<<dim3(H_ / 64, 512 / 64), blk, 0, stream>>>(
      q, Wq, qp, 512, H_, H_);
  // 2. kv projection -> bf16   grid 192*3=576
  gemm9r<768, __hip_bfloat16, false, false>
      <<<dim3((KVROWS / 256) * (H_ / 256)), blk9, 0, stream>>>(
      kbf, WkvT, nullptr, kvp, H_, H_ / 256);
  // 3. MFMA attention -> ares (bf16)
  attn_mfma<<<dim3(S_, NH_, B_), blk, 0, stream>>>(qp, kvp, mask, ares);
  // 4. ares @ Wo + bo -> d_out (f32 pre-LN scratch)   grid 96*3=288
  gemm9r<768, float, true, false>
      <<<dim3((MROWS / 256) * (H_ / 256)), blk9, 0, stream>>>(
      ares, WoT, bo, out, H_, H_ / 256);
  // 5. LN1: d_out -> aln (bf16)
  ln_kernel<false, float, __hip_bfloat16><<<MROWS, blk, 0, stream>>>(
      out, nullptr, ln1g, ln1b, aln);
  // 6. aln @ W1 + b1, gelu -> ffn1 (bf16)   grid 96*12=1152
  gemm9r<768, __hip_bfloat16, true, true>
      <<<dim3((MROWS / 256) * (FF_ / 256)), blk9, 0, stream>>>(
      aln, W1T, b1, ffn1, FF_, FF_ / 256);
  // 7. ffn1 @ W2 + b2 -> ffn2 (bf16)   grid 96*3=288, K=3072
  gemm9r<3072, __hip_bfloat16, true, false>
      <<<dim3((MROWS / 256) * (H_ / 256)), blk9, 0, stream>>>(
      ffn1, W2T, b2, ffn2, H_, H_ / 256);
  // 8. LN2: out = LN(aln + ffn2)
  ln_kernel<true, __hip_bfloat16, float><<<MROWS, blk, 0, stream>>>(
      aln, ffn2, ln2g, ln2b, out);
}

// Round 8
// 629.604 us; speedup vs baseline: 1.2668x; 1.2668x over previous
//
#include <hip/hip_runtime.h>
#include <hip/hip_bf16.h>
#include <math.h>

// Problem constants
#define B_ 8
#define Q_ 64
#define S_ 48
#define T_ 128
#define H_ 768
#define NH_ 12
#define HD_ 64
#define FF_ 3072

typedef float f32x4 __attribute__((ext_vector_type(4)));
typedef short s16x8 __attribute__((ext_vector_type(8)));
typedef short s16x4 __attribute__((ext_vector_type(4)));

__device__ __forceinline__ float ldT(const float* p, size_t i) { return p[i]; }
__device__ __forceinline__ float ldT(const __hip_bfloat16* p, size_t i) { return __bfloat162float(p[i]); }
__device__ __forceinline__ void stT(float* p, size_t i, float v) { p[i] = v; }
__device__ __forceinline__ void stT(__hip_bfloat16* p, size_t i, float v) { p[i] = __float2bfloat16(v); }

__device__ __forceinline__ short f2bf(float f) {
  __hip_bfloat16 h = __float2bfloat16(f);
  return *reinterpret_cast<short*>(&h);
}

__device__ __forceinline__ float gelu_f(float x) {
  return 0.5f * x * (1.0f + erff(x * 0.70710678118654752f));
}

// async global->LDS, 16B per lane
__device__ __forceinline__ void gld_lds16(const void* g, void* l) {
  __builtin_amdgcn_global_load_lds(
      (const __attribute__((address_space(1))) void*)g,
      (__attribute__((address_space(3))) void*)l, 16, 0, 0);
}

// ---------------------------------------------------------------------------
// MFMA bf16 GEMM (R5 structure): C[M,N] = act(A[M,K] @ BT[N,K]^T + bias)
// 128x128 tile, BK=32, 256 threads (4 waves, 2x2), each wave 64x64 out.
// 3-deep LDS pipeline with counted vmcnt: stage tile t+2 while computing
// tile t; wait vmcnt(4) = only tile t's 4 loads must have landed.
// Staging uses PERSISTENT per-thread pointers (+=32 elems per stage) to
// avoid per-K-step 64-bit address recompute (VALU was ~= MFMA time).
// Grid order: XCD-chunked + bm-grouped (G A-panels resident, bn inner)
// to cut per-XCD L2 B-thrash.
// Requires M%128==0, N%128==0, K%32==0, grid%8==0, cpx%(GB*nbx)==0.
// ---------------------------------------------------------------------------
__device__ __forceinline__ int swz_off(int row, int kc) {
  // byte offset of 16B chunk (row, k-chunk kc) in a [128][32] bf16 tile,
  // slot swizzled: slot = kc ^ ((row>>1)&3)  (involution)
  return row * 64 + ((kc ^ ((row >> 1) & 3)) << 4);
}

template<typename OT, bool BIAS, bool GELU>
__global__ __launch_bounds__(256) void gemm_mfma(
    const __hip_bfloat16* __restrict__ A,   // [M,K]
    const __hip_bfloat16* __restrict__ BT,  // [N,K]
    const float* __restrict__ bias, OT* __restrict__ C,
    int N, int K, int nbx, int GB)
{
  __shared__ char sm[3][16384];   // per buf: A at 0 (8KB), B at 8192 (8KB)

  // grid mapping: xcd chunk -> (g, bn, bi); bn inner over G-grouped bm
  const int cpx = gridDim.x >> 3;
  const int xcd = blockIdx.x & 7;
  const int ci  = blockIdx.x >> 3;
  const int gsz = GB * nbx;
  const int g   = ci / gsz;
  const int r2  = ci - g * gsz;
  const int bn  = r2 / GB;
  const int bi  = r2 - bn * GB;
  const int bm  = xcd * (cpx / nbx) + g * GB + bi;
  const int m0 = bm * 128, n0 = bn * 128;

  const int tid = threadIdx.x;
  const int lane = tid & 63;
  const int wid = tid >> 6;
  const int wr = wid >> 1, wc = wid & 1;

  const int nt = K >> 5;

  // persistent staging pointers (pre-swizzled source), advance 32 elems/stage
  const __hip_bfloat16* pA[2];
  const __hip_bfloat16* pB[2];
  #pragma unroll
  for (int r = 0; r < 2; ++r) {
    const int c = tid + r * 256, row = c >> 2, slot = c & 3;
    const int kc = slot ^ ((row >> 1) & 3);
    pA[r] = A + (size_t)(m0 + row) * K + kc * 8;
    pB[r] = BT + (size_t)(n0 + row) * K + kc * 8;
  }
  auto stage = [&](int buf) {
    char* smA = sm[buf];
    char* smB = sm[buf] + 8192;
    #pragma unroll
    for (int r = 0; r < 2; ++r) {
      const int c16 = (tid + r * 256) * 16;
      gld_lds16(pA[r], smA + c16); pA[r] += 32;
      gld_lds16(pB[r], smB + c16); pB[r] += 32;
    }
  };

  f32x4 acc[4][4] = {};
  stage(0);
  if (nt > 1) stage(1);

  int cur = 0;
  for (int kt = 0; kt < nt; ++kt) {
    // tile kt's 4 loads (per thread) are the oldest; tile kt+1's 4 may fly.
    if (kt + 1 < nt) asm volatile("s_waitcnt vmcnt(4)" ::: "memory");
    else             asm volatile("s_waitcnt vmcnt(0)" ::: "memory");
    __builtin_amdgcn_s_barrier();
    asm volatile("" ::: "memory");

    const char* smA = sm[cur];
    const char* smB = sm[cur] + 8192;
    const int kc = lane >> 4, rl = lane & 15;
    s16x8 af[4], bf[4];
    #pragma unroll
    for (int m = 0; m < 4; ++m)
      af[m] = *(const s16x8*)(smA + swz_off(wr * 64 + m * 16 + rl, kc));
    #pragma unroll
    for (int n = 0; n < 4; ++n)
      bf[n] = *(const s16x8*)(smB + swz_off(wc * 64 + n * 16 + rl, kc));

    // stage tile kt+2 into the buffer freed after iteration kt-1
    int nb = cur + 2; if (nb >= 3) nb -= 3;
    if (kt + 2 < nt) stage(nb);

    #pragma unroll
    for (int m = 0; m < 4; ++m)
      #pragma unroll
      for (int n = 0; n < 4; ++n)
        acc[m][n] = __builtin_amdgcn_mfma_f32_16x16x32_bf16(af[m], bf[n], acc[m][n], 0, 0, 0);

    ++cur; if (cur == 3) cur = 0;
  }

  // epilogue: C/D layout col=lane&15, row=(lane>>4)*4+r  [m89-verified]
  // n innermost so each 128B output line is written by consecutive stores.
  const int colb = n0 + wc * 64 + (lane & 15);
  const int rowb = m0 + wr * 64 + (lane >> 4) * 4;
  float bv[4];
  #pragma unroll
  for (int n = 0; n < 4; ++n) bv[n] = BIAS ? bias[colb + n * 16] : 0.0f;
  #pragma unroll
  for (int m = 0; m < 4; ++m) {
    #pragma unroll
    for (int r = 0; r < 4; ++r) {
      const int row = rowb + m * 16 + r;
      #pragma unroll
      for (int n = 0; n < 4; ++n) {
        float v = acc[m][n][r] + bv[n];
        if (GELU) v = gelu_f(v);
        stT(C, (size_t)row * N + colb + n * 16, v);
      }
    }
  }
}

// ---------------------------------------------------------------------------
// fp32 LDS-tiled GEMM (q-projection only), templated output
// ---------------------------------------------------------------------------
template<typename OT>
__global__ __launch_bounds__(256) void gemm64(
    const float* __restrict__ A, const float* __restrict__ W,
    OT* __restrict__ C, int M, int N, int K)
{
  __shared__ float As[16][65];
  __shared__ float Ws[16][65];
  const int tid = threadIdx.x;
  const int m0 = blockIdx.y * 64;
  const int n0 = blockIdx.x * 64;
  const int tx = (tid & 15) * 4;
  const int ty = (tid >> 4) * 4;
  float acc[4][4] = {};

  for (int k0 = 0; k0 < K; k0 += 16) {
    #pragma unroll
    for (int r = 0; r < 4; ++r) {
      int idx = tid + r * 256;
      int mm = idx >> 4, kk = idx & 15;
      As[kk][mm] = A[(size_t)(m0 + mm) * K + (k0 + kk)];
    }
    #pragma unroll
    for (int r = 0; r < 4; ++r) {
      int idx = tid + r * 256;
      int kk = idx >> 6, nn = idx & 63;
      Ws[kk][nn] = W[(size_t)(k0 + kk) * N + (n0 + nn)];
    }
    __syncthreads();
    #pragma unroll
    for (int kk = 0; kk < 16; ++kk) {
      float a[4], b[4];
      #pragma unroll
      for (int i = 0; i < 4; ++i) a[i] = As[kk][ty + i];
      #pragma unroll
      for (int j = 0; j < 4; ++j) b[j] = Ws[kk][tx + j];
      #pragma unroll
      for (int i = 0; i < 4; ++i)
        #pragma unroll
        for (int j = 0; j < 4; ++j) acc[i][j] += a[i] * b[j];
    }
    __syncthreads();
  }
  #pragma unroll
  for (int i = 0; i < 4; ++i)
    #pragma unroll
    for (int j = 0; j < 4; ++j)
      stT(C, (size_t)(m0 + ty + i) * N + (n0 + tx + j), acc[i][j]);
}

// ---------------------------------------------------------------------------
// weight transpose-cast: W[K,N] f32 -> WT[N,K] bf16
// ---------------------------------------------------------------------------
__global__ __launch_bounds__(256) void transpose_cast(
    const float* __restrict__ W, __hip_bfloat16* __restrict__ WT, int K, int N)
{
  __shared__ float t[32][33];
  const int n0 = blockIdx.x * 32, k0 = blockIdx.y * 32;
  const int x = threadIdx.x & 31, y4 = (threadIdx.x >> 5) * 4;
  #pragma unroll
  for (int i = 0; i < 4; ++i)
    t[y4 + i][x] = W[(size_t)(k0 + y4 + i) * N + n0 + x];
  __syncthreads();
  #pragma unroll
  for (int i = 0; i < 4; ++i)
    WT[(size_t)(n0 + y4 + i) * K + k0 + x] = __float2bfloat16(t[x][y4 + i]);
}

// elementwise cast f32 -> bf16, 4 elems/thread
__global__ __launch_bounds__(256) void cast_f32_bf16(
    const float* __restrict__ x, __hip_bfloat16* __restrict__ y, size_t n4)
{
  const size_t i = (size_t)blockIdx.x * 256 + threadIdx.x;
  if (i >= n4) return;
  const float4 v = ((const float4*)x)[i];
  __hip_bfloat16 o[4] = { __float2bfloat16(v.x), __float2bfloat16(v.y),
                          __float2bfloat16(v.z), __float2bfloat16(v.w) };
  *(ushort4*)(y + i * 4) = *(ushort4*)o;
}

// ---------------------------------------------------------------------------
// MFMA attention. Block = (s, h, b). 256 threads = 4 waves (2x2).  (R4, unchanged)
// ---------------------------------------------------------------------------
__global__ __launch_bounds__(256) void attn_mfma(
    const __hip_bfloat16* __restrict__ qp,   // [B*Q][H] bf16
    const __hip_bfloat16* __restrict__ kvp,  // [B*S*T][H] bf16
    const int* __restrict__ mask,
    __hip_bfloat16* __restrict__ res)        // [B,Q,S,H] bf16
{
  const int s = blockIdx.x, h = blockIdx.y, b = blockIdx.z;
  __shared__ __align__(16) char lds[66048];
  char* Ks = lds;
  char* VT = lds + 16384;
  char* SC = lds + 32768;
  float* mv = (float*)(lds + 65536);

  const int tid = threadIdx.x;
  const int lane = tid & 63;
  const int wid = tid >> 6;
  const int wr = wid >> 1, wc = wid & 1;
  const int kcg = lane >> 4, rl = lane & 15;

  if (tid < 128) mv[tid] = (float)mask[((size_t)b * S_ + s) * T_ + tid] * -10000.0f;

  {
    const __hip_bfloat16* qb = qp + ((size_t)b * Q_) * H_ + h * HD_;
    #pragma unroll
    for (int r = 0; r < 2; ++r) {
      const int c = tid + r * 256;
      const int qq = c >> 3, sc = c & 7;
      const int kc8 = sc ^ (qq & 7);
      gld_lds16(qb + (size_t)qq * H_ + kc8 * 8, SC + c * 16);
    }
  }
  {
    const int kc8 = tid & 7, tg = tid >> 3;
    const int t0 = tg * 4;
    const __hip_bfloat16* kb = kvp + (((size_t)b * S_ + s) * T_) * H_ + h * HD_ + kc8 * 8;
    s16x8 r0 = *(const s16x8*)(kb + (size_t)(t0 + 0) * H_);
    s16x8 r1 = *(const s16x8*)(kb + (size_t)(t0 + 1) * H_);
    s16x8 r2 = *(const s16x8*)(kb + (size_t)(t0 + 2) * H_);
    s16x8 r3 = *(const s16x8*)(kb + (size_t)(t0 + 3) * H_);
    *(s16x8*)(Ks + (t0 + 0) * 128 + ((kc8 ^ ((t0 + 0) & 7)) << 4)) = r0;
    *(s16x8*)(Ks + (t0 + 1) * 128 + ((kc8 ^ ((t0 + 1) & 7)) << 4)) = r1;
    *(s16x8*)(Ks + (t0 + 2) * 128 + ((kc8 ^ ((t0 + 2) & 7)) << 4)) = r2;
    *(s16x8*)(Ks + (t0 + 3) * 128 + ((kc8 ^ ((t0 + 3) & 7)) << 4)) = r3;
    const int tc = tg >> 1;
    const int toff = (tg & 1) * 8;
    #pragma unroll
    for (int j = 0; j < 8; ++j) {
      s16x4 v4 = { r0[j], r1[j], r2[j], r3[j] };
      const int d = kc8 * 8 + j;
      *(s16x4*)(VT + d * 256 + ((tc ^ (d & 15)) << 4) + toff) = v4;
    }
  }
  __syncthreads();

  f32x4 acc[2][4] = {};
  {
    s16x8 af[2][2], bf[2][4];
    #pragma unroll
    for (int kk = 0; kk < 2; ++kk) {
      #pragma unroll
      for (int m = 0; m < 2; ++m) {
        const int q = wr * 32 + m * 16 + rl;
        const int kc8 = kk * 4 + kcg;
        af[kk][m] = *(const s16x8*)(SC + q * 128 + ((kc8 ^ (q & 7)) << 4));
      }
      #pragma unroll
      for (int n = 0; n < 4; ++n) {
        const int t = wc * 64 + n * 16 + rl;
        const int kc8 = kk * 4 + kcg;
        bf[kk][n] = *(const s16x8*)(Ks + t * 128 + ((kc8 ^ (t & 7)) << 4));
      }
    }
    #pragma unroll
    for (int kk = 0; kk < 2; ++kk)
      #pragma unroll
      for (int m = 0; m < 2; ++m)
        #pragma unroll
        for (int n = 0; n < 4; ++n)
          acc[m][n] = __builtin_amdgcn_mfma_f32_16x16x32_bf16(af[kk][m], bf[kk][n], acc[m][n], 0, 0, 0);
  }
  __syncthreads();

  #pragma unroll
  for (int m = 0; m < 2; ++m)
    #pragma unroll
    for (int n = 0; n < 4; ++n)
      #pragma unroll
      for (int r = 0; r < 4; ++r) {
        const int q = wr * 32 + m * 16 + (lane >> 4) * 4 + r;
        const int t = wc * 64 + n * 16 + rl;
        const int tc32 = t >> 2;
        *(float*)(SC + q * 512 + ((tc32 ^ (q & 31)) << 4) + (t & 3) * 4) =
            acc[m][n][r] * 0.125f + mv[t];
      }
  __syncthreads();

  {
    const int q = tid >> 2, quarter = tid & 3;
    float vals[32];
    #pragma unroll
    for (int j = 0; j < 8; ++j) {
      const int tc32 = quarter * 8 + j;
      const f32x4 c = *(const f32x4*)(SC + q * 512 + ((tc32 ^ (q & 31)) << 4));
      vals[j * 4 + 0] = c[0]; vals[j * 4 + 1] = c[1];
      vals[j * 4 + 2] = c[2]; vals[j * 4 + 3] = c[3];
    }
    float mx = -1e30f;
    #pragma unroll
    for (int i = 0; i < 32; ++i) mx = fmaxf(mx, vals[i]);
    mx = fmaxf(mx, __shfl_xor(mx, 1, 64));
    mx = fmaxf(mx, __shfl_xor(mx, 2, 64));
    float sum = 0.0f;
    #pragma unroll
    for (int i = 0; i < 32; ++i) { vals[i] = expf(vals[i] - mx); sum += vals[i]; }
    sum += __shfl_xor(sum, 1, 64);
    sum += __shfl_xor(sum, 2, 64);
    const float inv = 1.0f / sum;
    #pragma unroll
    for (int jj = 0; jj < 4; ++jj) {
      const int tcp = quarter * 4 + jj;
      s16x8 pk;
      #pragma unroll
      for (int i = 0; i < 8; ++i) pk[i] = f2bf(vals[jj * 8 + i] * inv);
      *(s16x8*)(SC + q * 512 + ((tcp ^ (q & 15)) << 4)) = pk;
    }
  }
  __syncthreads();

  f32x4 oacc[2][2] = {};
  #pragma unroll
  for (int kt = 0; kt < 4; ++kt) {
    s16x8 pa[2], vb[2];
    #pragma unroll
    for (int m = 0; m < 2; ++m) {
      const int q = wr * 32 + m * 16 + rl;
      const int tcp = kt * 4 + kcg;
      pa[m] = *(const s16x8*)(SC + q * 512 + ((tcp ^ (q & 15)) << 4));
    }
    #pragma unroll
    for (int n = 0; n < 2; ++n) {
      const int d = wc * 32 + n * 16 + rl;
      const int tc = kt * 4 + kcg;
      vb[n] = *(const s16x8*)(VT + d * 256 + ((tc ^ (d & 15)) << 4));
    }
    #pragma unroll
    for (int m = 0; m < 2; ++m)
      #pragma unroll
      for (int n = 0; n < 2; ++n)
        oacc[m][n] = __builtin_amdgcn_mfma_f32_16x16x32_bf16(pa[m], vb[n], oacc[m][n], 0, 0, 0);
  }
  #pragma unroll
  for (int m = 0; m < 2; ++m)
    #pragma unroll
    for (int n = 0; n < 2; ++n)
      #pragma unroll
      for (int r = 0; r < 4; ++r) {
        const int q = wr * 32 + m * 16 + (lane >> 4) * 4 + r;
        const int d = wc * 32 + n * 16 + rl;
        res[(((size_t)b * Q_ + q) * S_ + s) * H_ + h * HD_ + d] =
            __float2bfloat16(oacc[m][n][r]);
      }
}

// ---------------------------------------------------------------------------
// Row LayerNorm over H=768, templated in/out dtypes.
// ---------------------------------------------------------------------------
template<bool ADD, typename IT, typename OT>
__global__ __launch_bounds__(256) void ln_kernel(
    const IT* __restrict__ X, const IT* __restrict__ X2,
    const float* __restrict__ g, const float* __restrict__ bta,
    OT* __restrict__ Y)
{
  const size_t row = blockIdx.x;
  const int tid = threadIdx.x;
  float v[3];
  #pragma unroll
  for (int i = 0; i < 3; ++i) {
    int c = tid + i * 256;
    v[i] = ldT(X, row * H_ + c);
    if (ADD) v[i] += ldT(X2, row * H_ + c);
  }
  float sum = v[0] + v[1] + v[2];
  #pragma unroll
  for (int off = 32; off > 0; off >>= 1) sum += __shfl_down(sum, off, 64);
  __shared__ float red[8];
  const int w = tid >> 6;
  if ((tid & 63) == 0) red[w] = sum;
  __syncthreads();
  const float mean = (red[0] + red[1] + red[2] + red[3]) * (1.0f / 768.0f);
  float vs = 0.0f;
  #pragma unroll
  for (int i = 0; i < 3; ++i) { v[i] -= mean; vs += v[i] * v[i]; }
  #pragma unroll
  for (int off = 32; off > 0; off >>= 1) vs += __shfl_down(vs, off, 64);
  if ((tid & 63) == 0) red[4 + w] = vs;
  __syncthreads();
  const float rstd = rsqrtf((red[4] + red[5] + red[6] + red[7]) * (1.0f / 768.0f) + 1e-12f);
  #pragma unroll
  for (int i = 0; i < 3; ++i) {
    int c = tid + i * 256;
    stT(Y, row * H_ + c, v[i] * rstd * g[c] + bta[c]);
  }
}

// ---------------------------------------------------------------------------
extern "C" void kernel_launch(void* const* d_in, const int* in_sizes, int n_in,
                              void* d_out, int out_size, void* d_ws, size_t ws_size,
                              hipStream_t stream) {
  const float* q    = (const float*)d_in[0];
  const float* k    = (const float*)d_in[1];
  const int*   mask = (const int*)d_in[2];
  const float* Wq   = (const float*)d_in[3];
  const float* Wkv  = (const float*)d_in[4];
  const float* Wo   = (const float*)d_in[5];
  const float* bo   = (const float*)d_in[6];
  const float* ln1g = (const float*)d_in[7];
  const float* ln1b = (const float*)d_in[8];
  const float* W1   = (const float*)d_in[9];
  const float* b1   = (const float*)d_in[10];
  const float* W2   = (const float*)d_in[11];
  const float* b2   = (const float*)d_in[12];
  const float* ln2g = (const float*)d_in[13];
  const float* ln2b = (const float*)d_in[14];
  float* out = (float*)d_out;

  const int MROWS = B_ * Q_ * S_;           // 24576
  const int KVROWS = B_ * S_ * T_;          // 49152

  // workspace layout (bytes), lifetime-based reuse:
  char* ws = (char*)d_ws;
  __hip_bfloat16* kbf  = (__hip_bfloat16*)ws;                        // 75.5MB [dead after kv gemm]
  __hip_bfloat16* apre = (__hip_bfloat16*)ws;                        // 37.7MB (reuses kbf; dead after LN1)
  __hip_bfloat16* kvp  = (__hip_bfloat16*)(ws + 75497472);           // 75.5MB [dead after attn]
  __hip_bfloat16* ffn1 = (__hip_bfloat16*)ws;                        // 151MB (reuses kbf/apre+kvp)
  __hip_bfloat16* ares = (__hip_bfloat16*)(ws + 150994944);          // 37.7MB [dead after Wo gemm]
  __hip_bfloat16* ffn2 = ares;                                       // reuse
  __hip_bfloat16* aln  = (__hip_bfloat16*)(ws + 188743680);          // 37.7MB
  __hip_bfloat16* qp   = (__hip_bfloat16*)(ws + 226492416);          // 0.8MB (bf16)
  __hip_bfloat16* WkvT = (__hip_bfloat16*)(ws + 228065280);
  __hip_bfloat16* WoT  = (__hip_bfloat16*)(ws + 229244928);
  __hip_bfloat16* W1T  = (__hip_bfloat16*)(ws + 230424576);
  __hip_bfloat16* W2T  = (__hip_bfloat16*)(ws + 235143168);

  dim3 blk(256);

  // weight prep
  transpose_cast<<<dim3(24, 24), blk, 0, stream>>>(Wkv, WkvT, H_, H_);
  transpose_cast<<<dim3(24, 24), blk, 0, stream>>>(Wo, WoT, H_, H_);
  transpose_cast<<<dim3(96, 24), blk, 0, stream>>>(W1, W1T, H_, FF_);
  transpose_cast<<<dim3(24, 96), blk, 0, stream>>>(W2, W2T, FF_, H_);
  cast_f32_bf16<<<dim3((KVROWS * H_ / 4 + 255) / 256), blk, 0, stream>>>(
      k, kbf, (size_t)KVROWS * H_ / 4);

  // 1. q projection (fp32 in, bf16 out)
  gemm64<__hip_bfloat16><<<dim3(H_ / 64, 512 / 64), blk, 0, stream>>>(
      q, Wq, qp, 512, H_, H_);
  // 2. kv projection -> bf16   grid 384*6=2304, cpx=288, GB=6 (gsz=36 | 288)
  gemm_mfma<__hip_bfloat16, false, false>
      <<<dim3((KVROWS / 128) * (H_ / 128)), blk, 0, stream>>>(
      kbf, WkvT, nullptr, kvp, H_, H_, H_ / 128, 6);
  // 3. MFMA attention -> ares (bf16)
  attn_mfma<<<dim3(S_, NH_, B_), blk, 0, stream>>>(qp, kvp, mask, ares);
  // 4. ares @ Wo + bo -> apre (bf16)   grid 192*6=1152, cpx=144, GB=6
  gemm_mfma<__hip_bfloat16, true, false>
      <<<dim3((MROWS / 128) * (H_ / 128)), blk, 0, stream>>>(
      ares, WoT, bo, apre, H_, H_, H_ / 128, 6);
  // 5. LN1: apre -> aln (bf16)
  ln_kernel<false, __hip_bfloat16, __hip_bfloat16><<<MROWS, blk, 0, stream>>>(
      apre, nullptr, ln1g, ln1b, aln);
  // 6. aln @ W1 + b1, gelu -> ffn1 (bf16)   grid 192*24=4608, cpx=576, GB=6
  gemm_mfma<__hip_bfloat16, true, true>
      <<<dim3((MROWS / 128) * (FF_ / 128)), blk, 0, stream>>>(
      aln, W1T, b1, ffn1, FF_, H_, FF_ / 128, 6);
  // 7. ffn1 @ W2 + b2 -> ffn2 (bf16)   grid 192*6=1152, cpx=144, GB=4 (A-panel 786KB)
  gemm_mfma<__hip_bfloat16, true, false>
      <<<dim3((MROWS / 128) * (H_ / 128)), blk, 0, stream>>>(
      ffn1, W2T, b2, ffn2, H_, FF_, H_ / 128, 4);
  // 8. LN2: out = LN(aln + ffn2)
  ln_kernel<true, __hip_bfloat16, float><<<MROWS, blk, 0, stream>>>(
      aln, ffn2, ln2g, ln2b, out);
}